// Round 3
// baseline (19700.494 us; speedup 1.0000x reference)
//
#include <hip/hip_runtime.h>

// Round 3: row-split design. WG = 512 threads (8 waves) owns 8 batch elements.
// Matvec phases: lane = (r,b) with r=row-within-octet, b=batch; wave w + pass p
// handles rowblock rb = p*8+w (8 gate-rows x 8 batch). Each weight is read ONCE
// per CU per step (was 8x redundant) as 128B coalesced blocks from a packed
// layout in d_ws. h/c vectors shared via LDS (broadcast reads), gates exchanged
// via LDS, layer 4 via in-wave shfl butterfly + wave-0 finish. 7 barriers/step.

typedef float v2f __attribute__((ext_vector_type(2)));

constexpr int BATCH   = 2048;
constexpr int T_STEPS = 256;
constexpr int H   = 51;
constexpr int G4  = 204;     // 4*H gate rows
constexpr int RB  = 26;      // rowblocks of 8 rows (208 padded rows)
constexpr int J4  = 13;      // j in blocks of 4 (52 padded cols)
constexpr int WBLK = 32;     // floats per (m,rb,j4) block: 8 rows x 4 cols
constexpr int WPM2 = RB * J4 * WBLK;   // 10816 floats per packed matrix
// wp2 total: 5*WPM2 floats = 216,320 bytes in d_ws

__device__ __forceinline__ float frcp(float x) { return __builtin_amdgcn_rcpf(x); }
__device__ __forceinline__ float sigmoid_f(float x) { float e = __expf(-x); return frcp(1.f + e); }
__device__ __forceinline__ float tanh_f(float x) {
    float xc = fminf(fmaxf(x, -15.f), 15.f);
    float e = __expf(2.f * xc);
    return 1.f - 2.f * frcp(e + 1.f);
}

// wp2[((m*RB+rb)*J4 + j4)*32 + r*4 + e] = Wm[rb*8+r][j4*4+e]  (0 if padded)
__global__ __launch_bounds__(256) void prep2(
    const float* __restrict__ w_hh1, const float* __restrict__ w_ih2,
    const float* __restrict__ w_hh2, const float* __restrict__ w_ih3,
    const float* __restrict__ w_hh3, float* __restrict__ wp2)
{
    int idx = blockIdx.x * 256 + threadIdx.x;
    if (idx >= 5 * WPM2) return;
    int e  = idx & 3;
    int rr = (idx >> 2) & 7;
    int j4 = (idx >> 5) % J4;
    int rb = (idx / (WBLK * J4)) % RB;
    int m  = idx / WPM2;
    int row = rb * 8 + rr, j = j4 * 4 + e;
    const float* W = (m == 0) ? w_hh1 : (m == 1) ? w_ih2 : (m == 2) ? w_hh2
                   : (m == 3) ? w_ih3 : w_hh3;
    wp2[idx] = (row < G4 && j < H) ? W[row * H + j] : 0.f;
}

__global__ __launch_bounds__(512, 2) void lstm4_main(
    const float* __restrict__ input, const float* __restrict__ wp2,
    const float* __restrict__ w_ih1,
    const float* __restrict__ b_ih1, const float* __restrict__ b_hh1,
    const float* __restrict__ b_ih2, const float* __restrict__ b_hh2,
    const float* __restrict__ b_ih3, const float* __restrict__ b_hh3,
    const float* __restrict__ w_ih4, const float* __restrict__ w_hh4,
    const float* __restrict__ b_ih4, const float* __restrict__ b_hh4,
    float* __restrict__ out)
{
    // LDS
    __shared__ float in_lds[8 * 260];      // input[b][t], stride 260 (bank-spread)
    __shared__ float xv[5 * 8 * 52];       // vectors: 0=h1 1=c1 2=h2 3=c2 4=h3; [v][b][j], j padded 52
    __shared__ float gl[G4 * 8];           // gate pre-activations [row][b]
    __shared__ float l4p[8 * 4 * 8];       // layer-4 partials [wave][q][b]
    __shared__ float c4l[8];               // c4 broadcast for the extra step

    const int tid  = threadIdx.x;
    const int wave = tid >> 6;
    const int r    = (tid >> 3) & 7;       // matvec: row-within-octet
    const int b    = tid & 7;              // batch-within-WG (both mappings share this)
    const int k    = tid >> 3;             // act phase: hidden unit 0..63
    const bool act_on = (k < H);
    const int  kc  = act_on ? k : (H - 1);

    // ---- preloads ----
    // matvec-lane constants: per pass p, row = (p*8+wave)*8 + r
    float wih1_p[4], cb1[4], cb2[4], cb3[4];
#pragma unroll
    for (int p = 0; p < 4; ++p) {
        int rb = p * 8 + wave;
        int row = rb * 8 + r;
        bool ok = (rb < RB) && (row < G4);
        int rw = ok ? row : 0;
        wih1_p[p] = ok ? w_ih1[rw] : 0.f;
        cb1[p] = ok ? (b_ih1[rw] + b_hh1[rw]) : 0.f;
        cb2[p] = ok ? (b_ih2[rw] + b_hh2[rw]) : 0.f;
        cb3[p] = ok ? (b_ih3[rw] + b_hh3[rw]) : 0.f;
    }
    // act-lane constants
    float wih4q[4];
#pragma unroll
    for (int q = 0; q < 4; ++q) wih4q[q] = act_on ? w_ih4[q * H + k] : 0.f;
    // wave-0 layer-4 constants (every lane of wave 0; q folded mod 4)
    const int q0 = (tid >> 3) & 3;
    float bias4 = b_ih4[q0] + b_hh4[q0];
    float whh4  = w_hh4[q0];

    // persistent per-(k,b) cell states
    float c1r = 0.f, c2r = 0.f, c3r = 0.f;
    // wave-0 layer-4 state (valid on lanes 0..7 = b; duplicated on 8..63)
    float h4 = 0.f, c4 = 0.f;

    // stage input block: WG covers flat input [blockIdx.x*2048, +2048)
    {
        const float4 iv = *(const float4*)(input + (size_t)blockIdx.x * 2048 + tid * 4);
        int bb = tid >> 6, tt = (tid & 63) * 4;
        *(float4*)(in_lds + bb * 260 + tt) = iv;
    }
    // zero the x-vectors (incl. j=51 pads)
    for (int i = tid; i < 5 * 8 * 52; i += 512) xv[i] = 0.f;
    if (tid < 8) c4l[tid] = 0.f;
    __syncthreads();

    for (int t = 0; t <= T_STEPS; ++t) {
        // ================= matvec A: gates1 = hh1 @ h1 + wih1*x + cb1 ==========
#pragma unroll
        for (int p = 0; p < 4; ++p) {
            int rb = p * 8 + wave;
            if (rb < RB) {
                v2f acc = {0.f, 0.f};
                const float* wb = wp2 + (size_t)((0 * RB + rb) * J4) * WBLK + r * 4;
                const float* xh = xv + (0 * 8 + b) * 52;
#pragma unroll
                for (int j4 = 0; j4 < J4; ++j4) {
                    float4 wh = *(const float4*)(wb + j4 * WBLK);
                    v2f h01 = *(const v2f*)(xh + j4 * 4);
                    v2f h23 = *(const v2f*)(xh + j4 * 4 + 2);
                    acc = __builtin_elementwise_fma((v2f){wh.x, wh.y}, h01, acc);
                    acc = __builtin_elementwise_fma((v2f){wh.z, wh.w}, h23, acc);
                }
                float xb = (t < T_STEPS) ? in_lds[b * 260 + t] : c4l[b];
                float g = acc.x + acc.y + cb1[p] + wih1_p[p] * xb;
                int row = rb * 8 + r;
                if (row < G4) gl[row * 8 + b] = g;
            }
        }
        __syncthreads();  // B1

        // ================= Act A ==========
        {
            float gi = gl[(0 * H + kc) * 8 + b], gf = gl[(1 * H + kc) * 8 + b];
            float gg = gl[(2 * H + kc) * 8 + b], go = gl[(3 * H + kc) * 8 + b];
            if (act_on) {
                float i_ = sigmoid_f(gi), f_ = sigmoid_f(gf);
                float g_ = tanh_f(gg), o_ = sigmoid_f(go);
                c1r = f_ * c1r + i_ * g_;
                float h1 = o_ * tanh_f(c1r);
                xv[(0 * 8 + b) * 52 + k] = h1;   // h1 for next step's mvA
                xv[(1 * 8 + b) * 52 + k] = c1r;  // c1: input to layer 2
            }
        }
        __syncthreads();  // B2

        // ================= matvec B: gates2 = ih2 @ c1 + hh2 @ h2 + cb2 ==========
#pragma unroll
        for (int p = 0; p < 4; ++p) {
            int rb = p * 8 + wave;
            if (rb < RB) {
                v2f acc = {0.f, 0.f};
                const float* wbi = wp2 + (size_t)((1 * RB + rb) * J4) * WBLK + r * 4;
                const float* wbh = wp2 + (size_t)((2 * RB + rb) * J4) * WBLK + r * 4;
                const float* xx = xv + (1 * 8 + b) * 52;
                const float* xh = xv + (2 * 8 + b) * 52;
#pragma unroll
                for (int j4 = 0; j4 < J4; ++j4) {
                    float4 wi = *(const float4*)(wbi + j4 * WBLK);
                    float4 wh = *(const float4*)(wbh + j4 * WBLK);
                    v2f x01 = *(const v2f*)(xx + j4 * 4);
                    v2f x23 = *(const v2f*)(xx + j4 * 4 + 2);
                    v2f h01 = *(const v2f*)(xh + j4 * 4);
                    v2f h23 = *(const v2f*)(xh + j4 * 4 + 2);
                    acc = __builtin_elementwise_fma((v2f){wi.x, wi.y}, x01, acc);
                    acc = __builtin_elementwise_fma((v2f){wi.z, wi.w}, x23, acc);
                    acc = __builtin_elementwise_fma((v2f){wh.x, wh.y}, h01, acc);
                    acc = __builtin_elementwise_fma((v2f){wh.z, wh.w}, h23, acc);
                }
                float g = acc.x + acc.y + cb2[p];
                int row = rb * 8 + r;
                if (row < G4) gl[row * 8 + b] = g;
            }
        }
        __syncthreads();  // B3

        // ================= Act B ==========
        {
            float gi = gl[(0 * H + kc) * 8 + b], gf = gl[(1 * H + kc) * 8 + b];
            float gg = gl[(2 * H + kc) * 8 + b], go = gl[(3 * H + kc) * 8 + b];
            if (act_on) {
                float i_ = sigmoid_f(gi), f_ = sigmoid_f(gf);
                float g_ = tanh_f(gg), o_ = sigmoid_f(go);
                c2r = f_ * c2r + i_ * g_;
                float h2 = o_ * tanh_f(c2r);
                xv[(2 * 8 + b) * 52 + k] = h2;   // h2 for next step's mvB
                xv[(3 * 8 + b) * 52 + k] = c2r;  // c2: input to layer 3
            }
        }
        __syncthreads();  // B4

        // ================= matvec C: gates3 = ih3 @ c2 + hh3 @ h3 + cb3 ==========
#pragma unroll
        for (int p = 0; p < 4; ++p) {
            int rb = p * 8 + wave;
            if (rb < RB) {
                v2f acc = {0.f, 0.f};
                const float* wbi = wp2 + (size_t)((3 * RB + rb) * J4) * WBLK + r * 4;
                const float* wbh = wp2 + (size_t)((4 * RB + rb) * J4) * WBLK + r * 4;
                const float* xx = xv + (3 * 8 + b) * 52;
                const float* xh = xv + (4 * 8 + b) * 52;
#pragma unroll
                for (int j4 = 0; j4 < J4; ++j4) {
                    float4 wi = *(const float4*)(wbi + j4 * WBLK);
                    float4 wh = *(const float4*)(wbh + j4 * WBLK);
                    v2f x01 = *(const v2f*)(xx + j4 * 4);
                    v2f x23 = *(const v2f*)(xx + j4 * 4 + 2);
                    v2f h01 = *(const v2f*)(xh + j4 * 4);
                    v2f h23 = *(const v2f*)(xh + j4 * 4 + 2);
                    acc = __builtin_elementwise_fma((v2f){wi.x, wi.y}, x01, acc);
                    acc = __builtin_elementwise_fma((v2f){wi.z, wi.w}, x23, acc);
                    acc = __builtin_elementwise_fma((v2f){wh.x, wh.y}, h01, acc);
                    acc = __builtin_elementwise_fma((v2f){wh.z, wh.w}, h23, acc);
                }
                float g = acc.x + acc.y + cb3[p];
                int row = rb * 8 + r;
                if (row < G4) gl[row * 8 + b] = g;
            }
        }
        __syncthreads();  // B5

        // ================= Act C + layer-4 butterfly ==========
        float p4[4];
        {
            float gi = gl[(0 * H + kc) * 8 + b], gf = gl[(1 * H + kc) * 8 + b];
            float gg = gl[(2 * H + kc) * 8 + b], go = gl[(3 * H + kc) * 8 + b];
            float c3v = 0.f;
            if (act_on) {
                float i_ = sigmoid_f(gi), f_ = sigmoid_f(gf);
                float g_ = tanh_f(gg), o_ = sigmoid_f(go);
                c3r = f_ * c3r + i_ * g_;
                float h3 = o_ * tanh_f(c3r);
                xv[(4 * 8 + b) * 52 + k] = h3;   // h3 for next step's mvC
                c3v = c3r;
            }
            // p4[q] = wih4[q][k]*c3[k][b]; reduce over k within wave (masks 8,16,32)
#pragma unroll
            for (int q = 0; q < 4; ++q) p4[q] = wih4q[q] * c3v;
#pragma unroll
            for (int m = 8; m < 64; m <<= 1) {
#pragma unroll
                for (int q = 0; q < 4; ++q) p4[q] += __shfl_xor(p4[q], m);
            }
            if ((tid & 63) < 8) {
#pragma unroll
                for (int q = 0; q < 4; ++q) l4p[(wave * 4 + q) * 8 + b] = p4[q];
            }
        }
        __syncthreads();  // B6

        // ================= layer-4 finish (wave 0) ==========
        if (wave == 0) {
            float s = 0.f;
#pragma unroll
            for (int w = 0; w < 8; ++w) s += l4p[(w * 4 + q0) * 8 + b];
            float h4b = __shfl(h4, b);                  // h4[b] lives on lane b
            float pre = s + bias4 + whh4 * h4b;
            float sv = sigmoid_f(pre), tv = tanh_f(pre);
            float actv = (q0 == 2) ? tv : sv;
            float iv = __shfl(actv, b);
            float fv = __shfl(actv, 8 + b);
            float gv = __shfl(actv, 16 + b);
            float ov = __shfl(actv, 24 + b);
            c4 = fv * c4 + iv * gv;
            h4 = ov * tanh_f(c4);
            if (tid < 8) c4l[tid] = c4;                 // for extra-step input
        }
        __syncthreads();  // B7
    }

    if (wave == 0 && tid < 8) out[blockIdx.x * 8 + tid] = c4;
}

extern "C" void kernel_launch(void* const* d_in, const int* in_sizes, int n_in,
                              void* d_out, int out_size, void* d_ws, size_t ws_size,
                              hipStream_t stream) {
    const float* input = (const float*)d_in[0];
    const float* w_ih1 = (const float*)d_in[1];
    const float* w_hh1 = (const float*)d_in[2];
    const float* b_ih1 = (const float*)d_in[3];
    const float* b_hh1 = (const float*)d_in[4];
    const float* w_ih2 = (const float*)d_in[5];
    const float* w_hh2 = (const float*)d_in[6];
    const float* b_ih2 = (const float*)d_in[7];
    const float* b_hh2 = (const float*)d_in[8];
    const float* w_ih3 = (const float*)d_in[9];
    const float* w_hh3 = (const float*)d_in[10];
    const float* b_ih3 = (const float*)d_in[11];
    const float* b_hh3 = (const float*)d_in[12];
    const float* w_ih4 = (const float*)d_in[13];
    const float* w_hh4 = (const float*)d_in[14];
    const float* b_ih4 = (const float*)d_in[15];
    const float* b_hh4 = (const float*)d_in[16];

    float* wp2 = (float*)d_ws;  // 216,320 bytes

    hipLaunchKernelGGL(prep2, dim3((5 * WPM2 + 255) / 256), dim3(256), 0, stream,
                       w_hh1, w_ih2, w_hh2, w_ih3, w_hh3, wp2);

    hipLaunchKernelGGL(lstm4_main, dim3(BATCH / 8), dim3(512), 0, stream,
                       input, wp2, w_ih1,
                       b_ih1, b_hh1, b_ih2, b_hh2, b_ih3, b_hh3,
                       w_ih4, w_hh4, b_ih4, b_hh4,
                       (float*)d_out);
}

// Round 4
// 1781.608 us; speedup vs baseline: 11.0577x; 11.0577x over previous
//
#include <hip/hip_runtime.h>
#include <hip/hip_fp16.h>

// Round 4: LDS-resident fp16 weights (fp32 math/states), row-split WG design.
// WG = 512 threads (8 waves) owns 8 batch elements, grid 256 (1 WG/CU).
// All 5 big matrices packed fp16 into LDS once (116 KB); inner loop touches
// NO global memory. x-vectors hoisted to registers per matvec. 6 barriers/step.

typedef _Float16 h8 __attribute__((ext_vector_type(8)));

constexpr int BATCH   = 2048;
constexpr int T_STEPS = 256;
constexpr int H   = 51;
constexpr int G4  = 204;          // 4*H gate rows
constexpr int RB  = 26;           // rowblocks of 8 rows (208 padded)
constexpr int J8  = 7;            // col-octets (56 padded cols, cols>=51 are 0)
constexpr int HPM = RB * J8 * 64; // halves per packed matrix = 11648
constexpr int WHALF = 5 * HPM;    // 58240 halves = 116480 B in d_ws / LDS
constexpr int XPAD = 60;          // x-vector row stride (bank-spread, j>=51 zero)

// LDS partition (bytes)
constexpr int LDS_W  = WHALF * 2;          // 116480
constexpr int LDS_XV = 5 * 8 * XPAD * 4;   //   9600
constexpr int LDS_GL = 208 * 8 * 4;        //   6656
constexpr int LDS_IN = 8 * 260 * 4;        //   8320
constexpr int LDS_L4 = 8 * 4 * 8 * 4;      //   1024
constexpr int LDS_TOTAL = LDS_W + LDS_XV + LDS_GL + LDS_IN + LDS_L4; // 142080

__device__ __forceinline__ float frcp(float x) { return __builtin_amdgcn_rcpf(x); }
__device__ __forceinline__ float sigmoid_f(float x) { float e = __expf(-x); return frcp(1.f + e); }
__device__ __forceinline__ float tanh_f(float x) {
    float xc = fminf(fmaxf(x, -15.f), 15.f);
    float e = __expf(2.f * xc);
    return 1.f - 2.f * frcp(e + 1.f);
}

// Pack fp32 -> fp16: wph[(m*RB+rb)*J8*64 + j8*64 + r*8 + e] = Wm[rb*8+r][j8*8+e]
__global__ __launch_bounds__(256) void prep3(
    const float* __restrict__ w_hh1, const float* __restrict__ w_ih2,
    const float* __restrict__ w_hh2, const float* __restrict__ w_ih3,
    const float* __restrict__ w_hh3, _Float16* __restrict__ wph)
{
    int idx = blockIdx.x * 256 + threadIdx.x;
    if (idx >= WHALF) return;
    int e  = idx & 7;
    int r  = (idx >> 3) & 7;
    int j8 = (idx >> 6) % J8;
    int rb = (idx / (64 * J8)) % RB;
    int m  = idx / HPM;
    int row = rb * 8 + r, j = j8 * 8 + e;
    const float* W = (m == 0) ? w_hh1 : (m == 1) ? w_ih2 : (m == 2) ? w_hh2
                   : (m == 3) ? w_ih3 : w_hh3;
    wph[idx] = (row < G4 && j < H) ? (_Float16)W[row * H + j] : (_Float16)0.f;
}

__global__ __launch_bounds__(512, 2) void lstm4_main(
    const float* __restrict__ input, const _Float16* __restrict__ wph,
    const float* __restrict__ w_ih1,
    const float* __restrict__ b_ih1, const float* __restrict__ b_hh1,
    const float* __restrict__ b_ih2, const float* __restrict__ b_hh2,
    const float* __restrict__ b_ih3, const float* __restrict__ b_hh3,
    const float* __restrict__ w_ih4, const float* __restrict__ w_hh4,
    const float* __restrict__ b_ih4, const float* __restrict__ b_hh4,
    float* __restrict__ out)
{
    extern __shared__ char smem[];
    _Float16* wl   = (_Float16*)smem;                    // [5][RB][J8][8r][8e]
    float*    xv   = (float*)(smem + LDS_W);             // [5 vec][8 b][XPAD]
    float*    gl   = (float*)(smem + LDS_W + LDS_XV);    // [208 row][8 b]
    float*    inl  = (float*)(smem + LDS_W + LDS_XV + LDS_GL);  // [8 b][260]
    float*    l4p  = (float*)(smem + LDS_W + LDS_XV + LDS_GL + LDS_IN); // [8w][4q][8b]

    const int tid  = threadIdx.x;
    const int wave = tid >> 6;
    const int r    = (tid >> 3) & 7;   // matvec: row-within-octet
    const int b    = tid & 7;          // batch-within-WG (shared by both mappings)
    const int k    = tid >> 3;         // act: hidden unit 0..63 (= wave*8 + r)
    const bool act_on = (k < H);
    const int  kc  = act_on ? k : (H - 1);
    const int  q0  = (tid >> 3) & 3;   // layer-4 finish gate index

    // ---- stage weights global -> LDS (coalesced uint4) ----
    {
        const uint4* src = (const uint4*)wph;
        uint4* dst = (uint4*)wl;
        for (int i = tid; i < LDS_W / 16; i += 512) dst[i] = src[i];
    }
    // ---- stage input block ----
    {
        const float4 iv = *(const float4*)(input + (size_t)blockIdx.x * 2048 + tid * 4);
        int bb = tid >> 6, tt = (tid & 63) * 4;
        *(float4*)(inl + bb * 260 + tt) = iv;
    }
    // ---- zero x-vectors (incl. pads) ----
    for (int i = tid; i < 5 * 8 * XPAD; i += 512) xv[i] = 0.f;

    // ---- per-lane constants ----
    float wih1_p[4], cb1[4], cb2[4], cb3[4];
#pragma unroll
    for (int p = 0; p < 4; ++p) {
        int rb = p * 8 + wave;
        int row = rb * 8 + r;
        bool ok = (rb < RB) && (row < G4);
        int rw = ok ? row : 0;
        wih1_p[p] = ok ? w_ih1[rw] : 0.f;
        cb1[p] = ok ? (b_ih1[rw] + b_hh1[rw]) : 0.f;
        cb2[p] = ok ? (b_ih2[rw] + b_hh2[rw]) : 0.f;
        cb3[p] = ok ? (b_ih3[rw] + b_hh3[rw]) : 0.f;
    }
    float wih4q[4];
#pragma unroll
    for (int q = 0; q < 4; ++q) wih4q[q] = act_on ? w_ih4[q * H + k] : 0.f;
    const float bias4 = b_ih4[q0] + b_hh4[q0];
    const float whh4  = w_hh4[q0];

    float c1r = 0.f, c2r = 0.f, c3r = 0.f;
    float h4 = 0.f, c4 = 0.f;   // replicated per lane (valid for lane's b)

    __syncthreads();

    for (int t = 0; t <= T_STEPS; ++t) {
        // ================= matvec A: gates1 = hh1 @ h1 + wih1*x + cb1 ==========
        {
            float xr[56];
#pragma unroll
            for (int j4 = 0; j4 < 14; ++j4) {
                float4 v = *(const float4*)(xv + (0 * 8 + b) * XPAD + j4 * 4);
                xr[j4*4+0]=v.x; xr[j4*4+1]=v.y; xr[j4*4+2]=v.z; xr[j4*4+3]=v.w;
            }
            const float xb = (t < T_STEPS) ? inl[b * 260 + t] : c4;
#pragma unroll
            for (int p = 0; p < 4; ++p) {
                int rb = p * 8 + wave;
                if (rb < RB) {
                    float acc = fmaf(wih1_p[p], xb, cb1[p]);
                    const _Float16* wrow = wl + (size_t)((0 * RB + rb) * J8) * 64 + r * 8;
#pragma unroll
                    for (int j8 = 0; j8 < J8; ++j8) {
                        h8 wq = *(const h8*)(wrow + j8 * 64);
#pragma unroll
                        for (int e = 0; e < 8; ++e)
                            acc = fmaf((float)wq[e], xr[j8 * 8 + e], acc);
                    }
                    int row = rb * 8 + r;
                    if (row < G4) gl[row * 8 + b] = acc;
                }
            }
        }
        __syncthreads();  // B1

        // ================= Act A ==========
        {
            float gi = gl[(0 * H + kc) * 8 + b], gf = gl[(1 * H + kc) * 8 + b];
            float gg = gl[(2 * H + kc) * 8 + b], go = gl[(3 * H + kc) * 8 + b];
            if (act_on) {
                float i_ = sigmoid_f(gi), f_ = sigmoid_f(gf);
                float g_ = tanh_f(gg), o_ = sigmoid_f(go);
                c1r = f_ * c1r + i_ * g_;
                float h1 = o_ * tanh_f(c1r);
                xv[(0 * 8 + b) * XPAD + k] = h1;
                xv[(1 * 8 + b) * XPAD + k] = c1r;
            }
        }
        __syncthreads();  // B2

        // ================= matvec B: gates2 = ih2 @ c1 + hh2 @ h2 + cb2 ==========
        {
            float xr1[56], xr2[56];
#pragma unroll
            for (int j4 = 0; j4 < 14; ++j4) {
                float4 v1 = *(const float4*)(xv + (1 * 8 + b) * XPAD + j4 * 4);
                float4 v2 = *(const float4*)(xv + (2 * 8 + b) * XPAD + j4 * 4);
                xr1[j4*4+0]=v1.x; xr1[j4*4+1]=v1.y; xr1[j4*4+2]=v1.z; xr1[j4*4+3]=v1.w;
                xr2[j4*4+0]=v2.x; xr2[j4*4+1]=v2.y; xr2[j4*4+2]=v2.z; xr2[j4*4+3]=v2.w;
            }
#pragma unroll
            for (int p = 0; p < 4; ++p) {
                int rb = p * 8 + wave;
                if (rb < RB) {
                    float acc = cb2[p];
                    const _Float16* wi = wl + (size_t)((1 * RB + rb) * J8) * 64 + r * 8;
                    const _Float16* wh = wl + (size_t)((2 * RB + rb) * J8) * 64 + r * 8;
#pragma unroll
                    for (int j8 = 0; j8 < J8; ++j8) {
                        h8 wq1 = *(const h8*)(wi + j8 * 64);
                        h8 wq2 = *(const h8*)(wh + j8 * 64);
#pragma unroll
                        for (int e = 0; e < 8; ++e) {
                            acc = fmaf((float)wq1[e], xr1[j8 * 8 + e], acc);
                            acc = fmaf((float)wq2[e], xr2[j8 * 8 + e], acc);
                        }
                    }
                    int row = rb * 8 + r;
                    if (row < G4) gl[row * 8 + b] = acc;
                }
            }
        }
        __syncthreads();  // B3

        // ================= Act B ==========
        {
            float gi = gl[(0 * H + kc) * 8 + b], gf = gl[(1 * H + kc) * 8 + b];
            float gg = gl[(2 * H + kc) * 8 + b], go = gl[(3 * H + kc) * 8 + b];
            if (act_on) {
                float i_ = sigmoid_f(gi), f_ = sigmoid_f(gf);
                float g_ = tanh_f(gg), o_ = sigmoid_f(go);
                c2r = f_ * c2r + i_ * g_;
                float h2 = o_ * tanh_f(c2r);
                xv[(2 * 8 + b) * XPAD + k] = h2;
                xv[(3 * 8 + b) * XPAD + k] = c2r;
            }
        }
        __syncthreads();  // B4

        // ================= matvec C: gates3 = ih3 @ c2 + hh3 @ h3 + cb3 ==========
        {
            float xr1[56], xr2[56];
#pragma unroll
            for (int j4 = 0; j4 < 14; ++j4) {
                float4 v1 = *(const float4*)(xv + (3 * 8 + b) * XPAD + j4 * 4);
                float4 v2 = *(const float4*)(xv + (4 * 8 + b) * XPAD + j4 * 4);
                xr1[j4*4+0]=v1.x; xr1[j4*4+1]=v1.y; xr1[j4*4+2]=v1.z; xr1[j4*4+3]=v1.w;
                xr2[j4*4+0]=v2.x; xr2[j4*4+1]=v2.y; xr2[j4*4+2]=v2.z; xr2[j4*4+3]=v2.w;
            }
#pragma unroll
            for (int p = 0; p < 4; ++p) {
                int rb = p * 8 + wave;
                if (rb < RB) {
                    float acc = cb3[p];
                    const _Float16* wi = wl + (size_t)((3 * RB + rb) * J8) * 64 + r * 8;
                    const _Float16* wh = wl + (size_t)((4 * RB + rb) * J8) * 64 + r * 8;
#pragma unroll
                    for (int j8 = 0; j8 < J8; ++j8) {
                        h8 wq1 = *(const h8*)(wi + j8 * 64);
                        h8 wq2 = *(const h8*)(wh + j8 * 64);
#pragma unroll
                        for (int e = 0; e < 8; ++e) {
                            acc = fmaf((float)wq1[e], xr1[j8 * 8 + e], acc);
                            acc = fmaf((float)wq2[e], xr2[j8 * 8 + e], acc);
                        }
                    }
                    int row = rb * 8 + r;
                    if (row < G4) gl[row * 8 + b] = acc;
                }
            }
        }
        __syncthreads();  // B5

        // ================= Act C + layer-4 butterfly ==========
        {
            float gi = gl[(0 * H + kc) * 8 + b], gf = gl[(1 * H + kc) * 8 + b];
            float gg = gl[(2 * H + kc) * 8 + b], go = gl[(3 * H + kc) * 8 + b];
            float c3v = 0.f;
            if (act_on) {
                float i_ = sigmoid_f(gi), f_ = sigmoid_f(gf);
                float g_ = tanh_f(gg), o_ = sigmoid_f(go);
                c3r = f_ * c3r + i_ * g_;
                float h3 = o_ * tanh_f(c3r);
                xv[(4 * 8 + b) * XPAD + k] = h3;
                c3v = c3r;
            }
            float p4[4];
#pragma unroll
            for (int q = 0; q < 4; ++q) p4[q] = wih4q[q] * c3v;
#pragma unroll
            for (int m = 8; m < 64; m <<= 1) {
#pragma unroll
                for (int q = 0; q < 4; ++q) p4[q] += __shfl_xor(p4[q], m);
            }
            if ((tid & 63) < 8) {
#pragma unroll
                for (int q = 0; q < 4; ++q) l4p[(wave * 4 + q) * 8 + b] = p4[q];
            }
        }
        __syncthreads();  // B6

        // ================= layer-4 finish (all waves, redundant) ==========
        {
            float s = 0.f;
#pragma unroll
            for (int w = 0; w < 8; ++w) s += l4p[(w * 4 + q0) * 8 + b];
            float pre = s + bias4 + whh4 * h4;
            float sv = sigmoid_f(pre), tv = tanh_f(pre);
            float actv = (q0 == 2) ? tv : sv;
            float iv = __shfl(actv, 0 * 8 + b);
            float fv = __shfl(actv, 1 * 8 + b);
            float gv = __shfl(actv, 2 * 8 + b);
            float ov = __shfl(actv, 3 * 8 + b);
            c4 = fv * c4 + iv * gv;
            h4 = ov * tanh_f(c4);
        }
        // no barrier: next mvA only reads xv (pre-B2) / writes gl (read pre-B6)
    }

    if (tid < 8) out[blockIdx.x * 8 + tid] = c4;
}

extern "C" void kernel_launch(void* const* d_in, const int* in_sizes, int n_in,
                              void* d_out, int out_size, void* d_ws, size_t ws_size,
                              hipStream_t stream) {
    const float* input = (const float*)d_in[0];
    const float* w_ih1 = (const float*)d_in[1];
    const float* w_hh1 = (const float*)d_in[2];
    const float* b_ih1 = (const float*)d_in[3];
    const float* b_hh1 = (const float*)d_in[4];
    const float* w_ih2 = (const float*)d_in[5];
    const float* w_hh2 = (const float*)d_in[6];
    const float* b_ih2 = (const float*)d_in[7];
    const float* b_hh2 = (const float*)d_in[8];
    const float* w_ih3 = (const float*)d_in[9];
    const float* w_hh3 = (const float*)d_in[10];
    const float* b_ih3 = (const float*)d_in[11];
    const float* b_hh3 = (const float*)d_in[12];
    const float* w_ih4 = (const float*)d_in[13];
    const float* w_hh4 = (const float*)d_in[14];
    const float* b_ih4 = (const float*)d_in[15];
    const float* b_hh4 = (const float*)d_in[16];

    _Float16* wph = (_Float16*)d_ws;  // 116,480 bytes

    static int attr_set = 0;
    (void)hipFuncSetAttribute((const void*)lstm4_main,
                              hipFuncAttributeMaxDynamicSharedMemorySize, LDS_TOTAL);
    (void)attr_set;

    hipLaunchKernelGGL(prep3, dim3((WHALF + 255) / 256), dim3(256), 0, stream,
                       w_hh1, w_ih2, w_hh2, w_ih3, w_hh3, wph);

    hipLaunchKernelGGL(lstm4_main, dim3(BATCH / 8), dim3(512), LDS_TOTAL, stream,
                       input, wph, w_ih1,
                       b_ih1, b_hh1, b_ih2, b_hh2, b_ih3, b_hh3,
                       w_ih4, w_hh4, b_ih4, b_hh4,
                       (float*)d_out);
}

// Round 5
// 599.885 us; speedup vs baseline: 32.8405x; 2.9699x over previous
//
#include <hip/hip_runtime.h>

// Round 5: MFMA path. Weights pre-packed (prep kernel) into v_mfma_f32_16x16x32_f16
// A-fragment layout and held in VGPRs for the whole kernel (zero weight traffic in
// the main loop). x-vectors stored fp16 in LDS, read as B-fragments (10 ds_read_b128
// per wave per step). gates = MFMA (fp32 accum); act/layer-4 phases scalar fp32 as
// round 4. WG = 512 thr (8 waves) owns 8 batch; grid 256 (1 WG/CU). 6 barriers/step.

typedef _Float16 f16x8 __attribute__((ext_vector_type(8)));
typedef float    f32x4 __attribute__((ext_vector_type(4)));

constexpr int BATCH   = 2048;
constexpr int T_STEPS = 256;
constexpr int H   = 51;
constexpr int G4  = 204;       // 4*H gate rows
constexpr int NTILE = 13;      // 16-row output tiles (208 padded rows)
constexpr int NUNIT = 5 * NTILE * 2;   // (matrix, tile, kf) units = 130
constexpr int GLP  = 9;        // gl row stride (bank spread)
constexpr int XKP  = 72;       // xh k-stride (halves; 144 B, 16B-aligned, bank spread)

__device__ __forceinline__ float frcp(float x) { return __builtin_amdgcn_rcpf(x); }
__device__ __forceinline__ float sigmoid_f(float x) { float e = __expf(-x); return frcp(1.f + e); }
__device__ __forceinline__ float tanh_f(float x) {
    float xc = fminf(fmaxf(x, -15.f), 15.f);
    float e = __expf(2.f * xc);
    return 1.f - 2.f * frcp(e + 1.f);
}

// Pack weights into MFMA A-fragment layout, fp16:
// unit u = (pm*13 + tile)*2 + kf;  pm: 0=hh1(+wih1 at k=51) 1=ih2 2=hh2 3=ih3 4=hh3
// wpa[u*512 + lane*8 + e] = A[tile*16 + (lane&15)][kf*32 + (lane>>4)*8 + e]
__global__ __launch_bounds__(256) void prep_mfma(
    const float* __restrict__ w_ih1, const float* __restrict__ w_hh1,
    const float* __restrict__ w_ih2, const float* __restrict__ w_hh2,
    const float* __restrict__ w_ih3, const float* __restrict__ w_hh3,
    _Float16* __restrict__ wpa)
{
    int id = blockIdx.x * 256 + threadIdx.x;
    if (id >= NUNIT * 64) return;
    int u = id >> 6, l = id & 63;
    int pm = u / 26;
    int tile = (u % 26) >> 1;
    int kf = u & 1;
    const float* W = (pm == 0) ? w_hh1 : (pm == 1) ? w_ih2 : (pm == 2) ? w_hh2
                   : (pm == 3) ? w_ih3 : w_hh3;
    int row = tile * 16 + (l & 15);
    int kbase = kf * 32 + ((l >> 4) << 3);
    f16x8 v;
#pragma unroll
    for (int e = 0; e < 8; ++e) {
        int k = kbase + e;
        float val = 0.f;
        if (row < G4) {
            if (k < H)                     val = W[row * H + k];
            else if (k == H && pm == 0)    val = w_ih1[row];   // x_t column
        }
        v[e] = (_Float16)val;
    }
    *(f16x8*)(wpa + (size_t)u * 512 + l * 8) = v;
}

__global__ __launch_bounds__(512, 2) void lstm4_main(
    const float* __restrict__ input, const _Float16* __restrict__ wpa,
    const float* __restrict__ b_ih1, const float* __restrict__ b_hh1,
    const float* __restrict__ b_ih2, const float* __restrict__ b_hh2,
    const float* __restrict__ b_ih3, const float* __restrict__ b_hh3,
    const float* __restrict__ w_ih4, const float* __restrict__ w_hh4,
    const float* __restrict__ b_ih4, const float* __restrict__ b_hh4,
    float* __restrict__ out)
{
    // LDS: x-vectors fp16 (0=h1[+x at k=51] 1=c1 2=h2 3=c2 4=h3), gates, input, l4 partials
    __shared__ __align__(16) _Float16 xh[5][8][XKP];   // 5760 B
    __shared__ float gl[208 * GLP];                    // 7488 B
    __shared__ float inl[8 * 260];                     // 8320 B
    __shared__ float l4p[8 * 4 * 8];                   // 1024 B

    const int tid  = threadIdx.x;
    const int wave = tid >> 6;
    const int lane = tid & 63;
    const int col  = lane & 15;    // mfma C/D col, B col
    const int rg   = lane >> 4;    // mfma row-group / k-group
    const int bcol = lane & 7;     // batch index for B-frag reads (cols 8-15 duplicate)
    const int k    = tid >> 3;     // act: hidden unit 0..63
    const int b    = tid & 7;      // batch-within-WG
    const bool act_on = (k < H);
    const int  kc  = act_on ? k : (H - 1);
    const int  q0  = (tid >> 3) & 3;

    // ---- load weight fragments into registers (persistent) ----
    const int tile0 = wave;
    const int tile1 = (wave < 5) ? (8 + wave) : wave;   // dummy for waves 5-7
    const bool two  = (wave < 5);
    auto LF = [&](int pm, int tile, int kf) -> f16x8 {
        int u = (pm * NTILE + tile) * 2 + kf;
        return *(const f16x8*)(wpa + (size_t)u * 512 + lane * 8);
    };
    const f16x8 fA_0k0 = LF(0, tile0, 0), fA_0k1 = LF(0, tile0, 1);
    const f16x8 fA_1k0 = LF(0, tile1, 0), fA_1k1 = LF(0, tile1, 1);
    const f16x8 fI2_0k0 = LF(1, tile0, 0), fI2_0k1 = LF(1, tile0, 1);
    const f16x8 fI2_1k0 = LF(1, tile1, 0), fI2_1k1 = LF(1, tile1, 1);
    const f16x8 fH2_0k0 = LF(2, tile0, 0), fH2_0k1 = LF(2, tile0, 1);
    const f16x8 fH2_1k0 = LF(2, tile1, 0), fH2_1k1 = LF(2, tile1, 1);
    const f16x8 fI3_0k0 = LF(3, tile0, 0), fI3_0k1 = LF(3, tile0, 1);
    const f16x8 fI3_1k0 = LF(3, tile1, 0), fI3_1k1 = LF(3, tile1, 1);
    const f16x8 fH3_0k0 = LF(4, tile0, 0), fH3_0k1 = LF(4, tile0, 1);
    const f16x8 fH3_1k0 = LF(4, tile1, 0), fH3_1k1 = LF(4, tile1, 1);

    // ---- act-lane constants ----
    float acb1[4], acb2[4], acb3[4], wih4q[4];
#pragma unroll
    for (int q = 0; q < 4; ++q) {
        const int r = q * H + kc;
        acb1[q] = b_ih1[r] + b_hh1[r];
        acb2[q] = b_ih2[r] + b_hh2[r];
        acb3[q] = b_ih3[r] + b_hh3[r];
        wih4q[q] = act_on ? w_ih4[q * H + k] : 0.f;
    }
    const float bias4 = b_ih4[q0] + b_hh4[q0];
    const float whh4  = w_hh4[q0];

    // ---- stage input, zero x-vectors ----
    {
        const float4 iv = *(const float4*)(input + (size_t)blockIdx.x * 2048 + tid * 4);
        *(float4*)(inl + (tid >> 6) * 260 + (tid & 63) * 4) = iv;
    }
    for (int i = tid; i < 5 * 8 * XKP; i += 512) ((_Float16*)xh)[i] = (_Float16)0.f;
    __syncthreads();
    if (tid < 8) xh[0][tid][H] = (_Float16)inl[tid * 260];   // x for t=0
    __syncthreads();

    float c1r = 0.f, c2r = 0.f, c3r = 0.f;
    float h4 = 0.f, c4 = 0.f;   // replicated; valid for lane's b

    for (int t = 0; t <= T_STEPS; ++t) {
        // ========== mvA: gates1 = hh1 @ h1 + wih1 * x (k=51 col) ==========
        {
            const f16x8 bv0 = *(const f16x8*)&xh[0][bcol][rg * 8];
            const f16x8 bv1 = *(const f16x8*)&xh[0][bcol][32 + rg * 8];
            f32x4 acc0 = {0.f, 0.f, 0.f, 0.f};
            acc0 = __builtin_amdgcn_mfma_f32_16x16x32_f16(fA_0k0, bv0, acc0, 0, 0, 0);
            acc0 = __builtin_amdgcn_mfma_f32_16x16x32_f16(fA_0k1, bv1, acc0, 0, 0, 0);
            if (col < 8) {
                const int rb0 = (tile0 * 16 + rg * 4) * GLP + col;
#pragma unroll
                for (int rr = 0; rr < 4; ++rr) gl[rb0 + rr * GLP] = acc0[rr];
            }
            if (two) {
                f32x4 acc1 = {0.f, 0.f, 0.f, 0.f};
                acc1 = __builtin_amdgcn_mfma_f32_16x16x32_f16(fA_1k0, bv0, acc1, 0, 0, 0);
                acc1 = __builtin_amdgcn_mfma_f32_16x16x32_f16(fA_1k1, bv1, acc1, 0, 0, 0);
                if (col < 8) {
                    const int rb1 = (tile1 * 16 + rg * 4) * GLP + col;
#pragma unroll
                    for (int rr = 0; rr < 4; ++rr) gl[rb1 + rr * GLP] = acc1[rr];
                }
            }
        }
        __syncthreads();  // B1

        // ========== Act A ==========
        {
            const float gi = gl[(0 * H + kc) * GLP + b] + acb1[0];
            const float gf = gl[(1 * H + kc) * GLP + b] + acb1[1];
            const float gg = gl[(2 * H + kc) * GLP + b] + acb1[2];
            const float go = gl[(3 * H + kc) * GLP + b] + acb1[3];
            if (act_on) {
                const float i_ = sigmoid_f(gi), f_ = sigmoid_f(gf);
                const float g_ = tanh_f(gg), o_ = sigmoid_f(go);
                c1r = f_ * c1r + i_ * g_;
                const float h1 = o_ * tanh_f(c1r);
                xh[0][b][k] = (_Float16)h1;
                xh[1][b][k] = (_Float16)c1r;
            }
        }
        __syncthreads();  // B2

        // ========== mvB: gates2 = ih2 @ c1 + hh2 @ h2 ==========
        {
            const f16x8 bx0 = *(const f16x8*)&xh[1][bcol][rg * 8];
            const f16x8 bx1 = *(const f16x8*)&xh[1][bcol][32 + rg * 8];
            const f16x8 bh0 = *(const f16x8*)&xh[2][bcol][rg * 8];
            const f16x8 bh1 = *(const f16x8*)&xh[2][bcol][32 + rg * 8];
            f32x4 acc0 = {0.f, 0.f, 0.f, 0.f};
            acc0 = __builtin_amdgcn_mfma_f32_16x16x32_f16(fI2_0k0, bx0, acc0, 0, 0, 0);
            acc0 = __builtin_amdgcn_mfma_f32_16x16x32_f16(fI2_0k1, bx1, acc0, 0, 0, 0);
            acc0 = __builtin_amdgcn_mfma_f32_16x16x32_f16(fH2_0k0, bh0, acc0, 0, 0, 0);
            acc0 = __builtin_amdgcn_mfma_f32_16x16x32_f16(fH2_0k1, bh1, acc0, 0, 0, 0);
            if (col < 8) {
                const int rb0 = (tile0 * 16 + rg * 4) * GLP + col;
#pragma unroll
                for (int rr = 0; rr < 4; ++rr) gl[rb0 + rr * GLP] = acc0[rr];
            }
            if (two) {
                f32x4 acc1 = {0.f, 0.f, 0.f, 0.f};
                acc1 = __builtin_amdgcn_mfma_f32_16x16x32_f16(fI2_1k0, bx0, acc1, 0, 0, 0);
                acc1 = __builtin_amdgcn_mfma_f32_16x16x32_f16(fI2_1k1, bx1, acc1, 0, 0, 0);
                acc1 = __builtin_amdgcn_mfma_f32_16x16x32_f16(fH2_1k0, bh0, acc1, 0, 0, 0);
                acc1 = __builtin_amdgcn_mfma_f32_16x16x32_f16(fH2_1k1, bh1, acc1, 0, 0, 0);
                if (col < 8) {
                    const int rb1 = (tile1 * 16 + rg * 4) * GLP + col;
#pragma unroll
                    for (int rr = 0; rr < 4; ++rr) gl[rb1 + rr * GLP] = acc1[rr];
                }
            }
        }
        __syncthreads();  // B3

        // ========== Act B ==========
        {
            const float gi = gl[(0 * H + kc) * GLP + b] + acb2[0];
            const float gf = gl[(1 * H + kc) * GLP + b] + acb2[1];
            const float gg = gl[(2 * H + kc) * GLP + b] + acb2[2];
            const float go = gl[(3 * H + kc) * GLP + b] + acb2[3];
            if (act_on) {
                const float i_ = sigmoid_f(gi), f_ = sigmoid_f(gf);
                const float g_ = tanh_f(gg), o_ = sigmoid_f(go);
                c2r = f_ * c2r + i_ * g_;
                const float h2 = o_ * tanh_f(c2r);
                xh[2][b][k] = (_Float16)h2;
                xh[3][b][k] = (_Float16)c2r;
            }
        }
        __syncthreads();  // B4

        // ========== mvC: gates3 = ih3 @ c2 + hh3 @ h3 ==========
        {
            const f16x8 bx0 = *(const f16x8*)&xh[3][bcol][rg * 8];
            const f16x8 bx1 = *(const f16x8*)&xh[3][bcol][32 + rg * 8];
            const f16x8 bh0 = *(const f16x8*)&xh[4][bcol][rg * 8];
            const f16x8 bh1 = *(const f16x8*)&xh[4][bcol][32 + rg * 8];
            f32x4 acc0 = {0.f, 0.f, 0.f, 0.f};
            acc0 = __builtin_amdgcn_mfma_f32_16x16x32_f16(fI3_0k0, bx0, acc0, 0, 0, 0);
            acc0 = __builtin_amdgcn_mfma_f32_16x16x32_f16(fI3_0k1, bx1, acc0, 0, 0, 0);
            acc0 = __builtin_amdgcn_mfma_f32_16x16x32_f16(fH3_0k0, bh0, acc0, 0, 0, 0);
            acc0 = __builtin_amdgcn_mfma_f32_16x16x32_f16(fH3_0k1, bh1, acc0, 0, 0, 0);
            if (col < 8) {
                const int rb0 = (tile0 * 16 + rg * 4) * GLP + col;
#pragma unroll
                for (int rr = 0; rr < 4; ++rr) gl[rb0 + rr * GLP] = acc0[rr];
            }
            if (two) {
                f32x4 acc1 = {0.f, 0.f, 0.f, 0.f};
                acc1 = __builtin_amdgcn_mfma_f32_16x16x32_f16(fI3_1k0, bx0, acc1, 0, 0, 0);
                acc1 = __builtin_amdgcn_mfma_f32_16x16x32_f16(fI3_1k1, bx1, acc1, 0, 0, 0);
                acc1 = __builtin_amdgcn_mfma_f32_16x16x32_f16(fH3_1k0, bh0, acc1, 0, 0, 0);
                acc1 = __builtin_amdgcn_mfma_f32_16x16x32_f16(fH3_1k1, bh1, acc1, 0, 0, 0);
                if (col < 8) {
                    const int rb1 = (tile1 * 16 + rg * 4) * GLP + col;
#pragma unroll
                    for (int rr = 0; rr < 4; ++rr) gl[rb1 + rr * GLP] = acc1[rr];
                }
            }
        }
        __syncthreads();  // B5

        // ========== Act C + layer-4 butterfly ==========
        {
            const float gi = gl[(0 * H + kc) * GLP + b] + acb3[0];
            const float gf = gl[(1 * H + kc) * GLP + b] + acb3[1];
            const float gg = gl[(2 * H + kc) * GLP + b] + acb3[2];
            const float go = gl[(3 * H + kc) * GLP + b] + acb3[3];
            float c3v = 0.f;
            if (act_on) {
                const float i_ = sigmoid_f(gi), f_ = sigmoid_f(gf);
                const float g_ = tanh_f(gg), o_ = sigmoid_f(go);
                c3r = f_ * c3r + i_ * g_;
                const float h3 = o_ * tanh_f(c3r);
                xh[4][b][k] = (_Float16)h3;
                c3v = c3r;
            }
            float p4[4];
#pragma unroll
            for (int q = 0; q < 4; ++q) p4[q] = wih4q[q] * c3v;
#pragma unroll
            for (int m = 8; m < 64; m <<= 1) {
#pragma unroll
                for (int q = 0; q < 4; ++q) p4[q] += __shfl_xor(p4[q], m);
            }
            if (lane < 8) {
#pragma unroll
                for (int q = 0; q < 4; ++q) l4p[(wave * 4 + q) * 8 + b] = p4[q];
            }
            // stage next step's x_t (known in advance from input)
            if (k == H && t + 1 < T_STEPS) xh[0][b][H] = (_Float16)inl[b * 260 + t + 1];
        }
        __syncthreads();  // B6

        // ========== layer-4 finish (all waves, redundant) ==========
        {
            float s = 0.f;
#pragma unroll
            for (int w = 0; w < 8; ++w) s += l4p[(w * 4 + q0) * 8 + b];
            const float pre = s + bias4 + whh4 * h4;
            const float sv = sigmoid_f(pre), tv = tanh_f(pre);
            const float actv = (q0 == 2) ? tv : sv;
            const float iv = __shfl(actv, 0 * 8 + b);
            const float fv = __shfl(actv, 1 * 8 + b);
            const float gv = __shfl(actv, 2 * 8 + b);
            const float ov = __shfl(actv, 3 * 8 + b);
            c4 = fv * c4 + iv * gv;
            h4 = ov * tanh_f(c4);
        }
        if (t == T_STEPS - 1) {   // uniform: stage c4 as the extra step's input
            if (tid < 8) xh[0][tid][H] = (_Float16)c4;
            __syncthreads();
        }
    }

    if (tid < 8) out[blockIdx.x * 8 + tid] = c4;
}

extern "C" void kernel_launch(void* const* d_in, const int* in_sizes, int n_in,
                              void* d_out, int out_size, void* d_ws, size_t ws_size,
                              hipStream_t stream) {
    const float* input = (const float*)d_in[0];
    const float* w_ih1 = (const float*)d_in[1];
    const float* w_hh1 = (const float*)d_in[2];
    const float* b_ih1 = (const float*)d_in[3];
    const float* b_hh1 = (const float*)d_in[4];
    const float* w_ih2 = (const float*)d_in[5];
    const float* w_hh2 = (const float*)d_in[6];
    const float* b_ih2 = (const float*)d_in[7];
    const float* b_hh2 = (const float*)d_in[8];
    const float* w_ih3 = (const float*)d_in[9];
    const float* w_hh3 = (const float*)d_in[10];
    const float* b_ih3 = (const float*)d_in[11];
    const float* b_hh3 = (const float*)d_in[12];
    const float* w_ih4 = (const float*)d_in[13];
    const float* w_hh4 = (const float*)d_in[14];
    const float* b_ih4 = (const float*)d_in[15];
    const float* b_hh4 = (const float*)d_in[16];

    _Float16* wpa = (_Float16*)d_ws;  // 130 units * 512 halves = 133,120 bytes

    hipLaunchKernelGGL(prep_mfma, dim3((NUNIT * 64 + 255) / 256), dim3(256), 0, stream,
                       w_ih1, w_hh1, w_ih2, w_hh2, w_ih3, w_hh3, wpa);

    hipLaunchKernelGGL(lstm4_main, dim3(BATCH / 8), dim3(512), 0, stream,
                       input, wpa,
                       b_ih1, b_hh1, b_ih2, b_hh2, b_ih3, b_hh3,
                       w_ih4, w_hh4, b_ih4, b_hh4,
                       (float*)d_out);
}